// Round 1
// baseline (387.750 us; speedup 1.0000x reference)
//
#include <hip/hip_runtime.h>
#include <hip/hip_bf16.h>
#include <stdint.h>

// ---------------------------------------------------------------------------
// EncoderLayer: x[16,1024,512] fp32; all matmuls in bf16 MFMA, fp32 accum.
// ---------------------------------------------------------------------------

using bf16 = __bf16;
typedef __attribute__((ext_vector_type(8))) __bf16 bf16x8;
typedef __attribute__((ext_vector_type(4))) float floatx4;

#define AS1 __attribute__((address_space(1)))
#define AS3 __attribute__((address_space(3)))

#define L2E 1.44269504088896340736f

constexpr int BN_ = 16, SQ_ = 1024, DM_ = 512, DFF_ = 2048, NH_ = 8, DK_ = 64;
constexpr int ROWS_ = BN_ * SQ_;   // 16384

// ---------------------------------------------------------------- fp32->bf16
__global__ __launch_bounds__(256) void f2b_kernel(const float* __restrict__ in,
                                                  bf16* __restrict__ out, int n8) {
  int i = blockIdx.x * 256 + threadIdx.x;
  if (i >= n8) return;
  float4 a = ((const float4*)in)[2 * i];
  float4 b = ((const float4*)in)[2 * i + 1];
  bf16x8 o;
  o[0] = (bf16)a.x; o[1] = (bf16)a.y; o[2] = (bf16)a.z; o[3] = (bf16)a.w;
  o[4] = (bf16)b.x; o[5] = (bf16)b.y; o[6] = (bf16)b.z; o[7] = (bf16)b.w;
  ((bf16x8*)out)[i] = o;
}

// ------------------------------------------------------------------- GEMM
// C[M,N] = A[M,K] @ B[N,K]^T + bias, optional ReLU, bf16 out.
// 128x128 tile, BK=32, 4 waves each owning a 64x64 sub-tile (4x4 frags of
// 16x16x32 MFMA). Staging: global_load_lds width-16, linear LDS dest with
// inverse-swizzled global source; reads XOR-swizzled (rule #21) so
// ds_read_b128 is ~2-way (free).
template <int RELU>
__global__ __launch_bounds__(256) void gemm_bt(const bf16* __restrict__ A,
                                               const bf16* __restrict__ B,
                                               const float* __restrict__ bias,
                                               bf16* __restrict__ C,
                                               int M, int N, int K) {
  __shared__ bf16 As[128 * 32];
  __shared__ bf16 Bs[128 * 32];
  const int tid = threadIdx.x;
  const int lane = tid & 63;
  const int wv = tid >> 6;
  const int wr = wv >> 1, wc = wv & 1;
  const int r15 = lane & 15, g = lane >> 4;
  const int tileN = blockIdx.x * 128;
  const int tileM = blockIdx.y * 128;

  floatx4 acc[4][4] = {};

  const int nk = K >> 5;
  for (int kt = 0; kt < nk; ++kt) {
    const int k0 = kt << 5;
    __syncthreads();
#pragma unroll
    for (int is = 0; is < 2; ++is) {
      const int base = wv * 2048 + is * 1024;   // wave-uniform LDS byte base
      const int ob = base + lane * 16;          // this lane's dest chunk
      const int row = ob >> 6;                  // tile row (64B per row)
      const int pslot = (ob >> 4) & 3;          // physical 16B slot in row
      const int sslot = pslot ^ ((row >> 1) & 3);  // logical k-slot to fetch
      const bf16* ga = A + (size_t)(tileM + row) * K + (k0 + sslot * 8);
      __builtin_amdgcn_global_load_lds((AS1 uint32_t*)ga,
                                       (AS3 uint32_t*)((AS3 char*)As + base),
                                       16, 0, 0);
      const bf16* gb = B + (size_t)(tileN + row) * K + (k0 + sslot * 8);
      __builtin_amdgcn_global_load_lds((AS1 uint32_t*)gb,
                                       (AS3 uint32_t*)((AS3 char*)Bs + base),
                                       16, 0, 0);
    }
    __syncthreads();

    bf16x8 af[4], bfr[4];
#pragma unroll
    for (int m = 0; m < 4; ++m) {
      const int arow = wr * 64 + m * 16 + r15;
      const int ab = (arow * 64 + g * 16) ^ (((arow >> 1) & 3) << 4);
      af[m] = *(const bf16x8*)((const char*)As + ab);
    }
#pragma unroll
    for (int n = 0; n < 4; ++n) {
      const int brow = wc * 64 + n * 16 + r15;
      const int bb = (brow * 64 + g * 16) ^ (((brow >> 1) & 3) << 4);
      bfr[n] = *(const bf16x8*)((const char*)Bs + bb);
    }
#pragma unroll
    for (int m = 0; m < 4; ++m)
#pragma unroll
      for (int n = 0; n < 4; ++n)
        acc[m][n] = __builtin_amdgcn_mfma_f32_16x16x32_bf16(af[m], bfr[n],
                                                            acc[m][n], 0, 0, 0);
  }

  // epilogue: D layout col = lane&15, row = (lane>>4)*4 + reg   [m89]
#pragma unroll
  for (int n = 0; n < 4; ++n) {
    const int col = tileN + wc * 64 + n * 16 + r15;
    const float bv = bias[col];
#pragma unroll
    for (int m = 0; m < 4; ++m) {
      const int row0 = tileM + wr * 64 + m * 16 + g * 4;
#pragma unroll
      for (int j = 0; j < 4; ++j) {
        float v = acc[m][n][j] + bv;
        if (RELU) v = fmaxf(v, 0.f);
        C[(size_t)(row0 + j) * N + col] = (bf16)v;
      }
    }
  }
}

// ----------------------------------------------------------- flash attention
// Q = K = V = qkv[b,:,h*64:(h+1)*64].  One block = 128 q-rows of one (b,h).
// 4 waves x 32 q-rows. Online softmax, scale 1/8 pre-folded into Q (exact).
__global__ __launch_bounds__(256) void attn_kernel(const bf16* __restrict__ qkv,
                                                   bf16* __restrict__ ctx) {
  __shared__ bf16 Ks[128 * 64];        // 16KB, row stride 128B, swz ^((row&7)<<4)
  __shared__ bf16 Vts[64 * 128];       // 16KB transposed V, row stride 256B
  __shared__ bf16 Ps[4][32 * 128];     // 32KB, per-wave P, row stride 256B

  const int tid = threadIdx.x;
  const int lane = tid & 63;
  const int wv = tid >> 6;
  const int r15 = lane & 15, g = lane >> 4;
  const int b = blockIdx.z, h = blockIdx.y, qt = blockIdx.x;
  const size_t headoff = (size_t)b * SQ_ * DM_ + h * DK_;
  const int q0 = qt * 128 + wv * 32;

  // Q fragments, pre-scaled by 1/sqrt(64)=0.125 (exponent shift, exact in bf16)
  bf16x8 aq[2][2];
#pragma unroll
  for (int m = 0; m < 2; ++m)
#pragma unroll
    for (int ks = 0; ks < 2; ++ks) {
      const bf16* gq = qkv + headoff + (size_t)(q0 + m * 16 + r15) * DM_ + ks * 32 + g * 8;
      bf16x8 v = *(const bf16x8*)gq;
#pragma unroll
      for (int e = 0; e < 8; ++e) v[e] = (bf16)((float)v[e] * 0.125f);
      aq[m][ks] = v;
    }

  float mstate[2][4], lstate[2][4];
  floatx4 o[2][4] = {};
#pragma unroll
  for (int m = 0; m < 2; ++m)
#pragma unroll
    for (int j = 0; j < 4; ++j) { mstate[m][j] = -1e30f; lstate[m][j] = 0.f; }

  for (int kt = 0; kt < SQ_ / 128; ++kt) {
    __syncthreads();
    // ---- stage K tile (global_load_lds, swizzled source)
#pragma unroll
    for (int is = 0; is < 4; ++is) {
      const int base = wv * 4096 + is * 1024;
      const int ob = base + lane * 16;
      const int row = ob >> 7;                 // 128B per row
      const int pch = (ob >> 4) & 7;
      const int sch = pch ^ (row & 7);
      const bf16* gk = qkv + headoff + (size_t)(kt * 128 + row) * DM_ + sch * 8;
      __builtin_amdgcn_global_load_lds((AS1 uint32_t*)gk,
                                       (AS3 uint32_t*)((AS3 char*)Ks + base),
                                       16, 0, 0);
    }
    // ---- stage V transposed (scalar LDS writes)
#pragma unroll
    for (int it = 0; it < 4; ++it) {
      const int cid = tid + it * 256;          // 0..1023
      const int s = cid >> 3, dch = cid & 7;
      const bf16* gv = qkv + headoff + (size_t)(kt * 128 + s) * DM_ + dch * 8;
      bf16x8 v = *(const bf16x8*)gv;
#pragma unroll
      for (int e = 0; e < 8; ++e) {
        const int d = dch * 8 + e;
        const int byte = (d * 256 + s * 2) ^ ((d & 7) << 4);
        *(bf16*)((char*)Vts + byte) = v[e];
      }
    }
    __syncthreads();

    // ---- scores S = (Q/8) K^T  : per wave 32x128
    floatx4 sa[2][8];
#pragma unroll
    for (int n = 0; n < 8; ++n) {
      const int brow = n * 16 + r15;
      const int b0 = (brow * 128 + 0 + g * 16) ^ ((brow & 7) << 4);
      const int b1 = (brow * 128 + 64 + g * 16) ^ ((brow & 7) << 4);
      bf16x8 kb0 = *(const bf16x8*)((const char*)Ks + b0);
      bf16x8 kb1 = *(const bf16x8*)((const char*)Ks + b1);
#pragma unroll
      for (int m = 0; m < 2; ++m) {
        floatx4 z = {};
        z = __builtin_amdgcn_mfma_f32_16x16x32_bf16(aq[m][0], kb0, z, 0, 0, 0);
        sa[m][n] = __builtin_amdgcn_mfma_f32_16x16x32_bf16(aq[m][1], kb1, z, 0, 0, 0);
      }
    }

    // ---- online softmax (rows live in 16-lane groups sharing g)
#pragma unroll
    for (int m = 0; m < 2; ++m) {
      float vmax[4], nm[4], al[4], rsum[4];
#pragma unroll
      for (int j = 0; j < 4; ++j) {
        float v = sa[m][0][j];
#pragma unroll
        for (int n = 1; n < 8; ++n) v = fmaxf(v, sa[m][n][j]);
#pragma unroll
        for (int off = 1; off < 16; off <<= 1) v = fmaxf(v, __shfl_xor(v, off));
        vmax[j] = v;
        nm[j] = fmaxf(mstate[m][j], v);
        al[j] = exp2f((mstate[m][j] - nm[j]) * L2E);
        mstate[m][j] = nm[j];
        rsum[j] = 0.f;
      }
#pragma unroll
      for (int n = 0; n < 8; ++n)
#pragma unroll
        for (int j = 0; j < 4; ++j) {
          float p = exp2f((sa[m][n][j] - nm[j]) * L2E);
          sa[m][n][j] = p;
          rsum[j] += p;
        }
      // write P (bf16) to per-wave LDS
#pragma unroll
      for (int n = 0; n < 8; ++n)
#pragma unroll
        for (int j = 0; j < 4; ++j) {
          const int r = m * 16 + g * 4 + j;
          const int c = n * 16 + r15;
          const int byte = (r * 256 + c * 2) ^ ((r & 7) << 4);
          *(bf16*)((char*)Ps[wv] + byte) = (bf16)sa[m][n][j];
        }
#pragma unroll
      for (int j = 0; j < 4; ++j) {
#pragma unroll
        for (int off = 1; off < 16; off <<= 1) rsum[j] += __shfl_xor(rsum[j], off);
        lstate[m][j] = lstate[m][j] * al[j] + rsum[j];
      }
#pragma unroll
      for (int n = 0; n < 4; ++n)
#pragma unroll
        for (int j = 0; j < 4; ++j) o[m][n][j] *= al[j];
    }
    __syncthreads();

    // ---- PV: ctx += P[32,128] @ V[128,64]
#pragma unroll
    for (int ks = 0; ks < 4; ++ks) {
      bf16x8 pa[2], vb[4];
#pragma unroll
      for (int m = 0; m < 2; ++m) {
        const int r = m * 16 + r15;
        const int byte = (r * 256 + ks * 64 + g * 16) ^ ((r & 7) << 4);
        pa[m] = *(const bf16x8*)((const char*)Ps[wv] + byte);
      }
#pragma unroll
      for (int n = 0; n < 4; ++n) {
        const int r = n * 16 + r15;
        const int byte = (r * 256 + ks * 64 + g * 16) ^ ((r & 7) << 4);
        vb[n] = *(const bf16x8*)((const char*)Vts + byte);
      }
#pragma unroll
      for (int m = 0; m < 2; ++m)
#pragma unroll
        for (int n = 0; n < 4; ++n)
          o[m][n] = __builtin_amdgcn_mfma_f32_16x16x32_bf16(pa[m], vb[n], o[m][n], 0, 0, 0);
    }
  }

  // ---- epilogue: ctx = O / l
#pragma unroll
  for (int m = 0; m < 2; ++m) {
    float inv[4];
#pragma unroll
    for (int j = 0; j < 4; ++j) inv[j] = 1.f / lstate[m][j];
#pragma unroll
    for (int n = 0; n < 4; ++n)
#pragma unroll
      for (int j = 0; j < 4; ++j) {
        const int srow = q0 + m * 16 + g * 4 + j;
        const int col = h * DK_ + n * 16 + r15;
        ctx[(size_t)(b * SQ_ + srow) * DM_ + col] = (bf16)(o[m][n][j] * inv[j]);
      }
  }
}

// ------------------------------------------------- dual LayerNorm residual #1
// out_bf16 = LN(x)*g1+be1 + LN(attn)*g1+be1 ; one wave per row of 512.
__global__ __launch_bounds__(256) void dual_ln_kernel(const float* __restrict__ x,
                                                      const bf16* __restrict__ attn,
                                                      const float* __restrict__ g1,
                                                      const float* __restrict__ be1,
                                                      bf16* __restrict__ out) {
  const int row = blockIdx.x * 4 + (threadIdx.x >> 6);
  const int lane = threadIdx.x & 63;
  const float* xr = x + (size_t)row * DM_ + lane * 8;
  float xs[8], as_[8];
  float4 t0 = ((const float4*)xr)[0];
  float4 t1 = ((const float4*)xr)[1];
  xs[0] = t0.x; xs[1] = t0.y; xs[2] = t0.z; xs[3] = t0.w;
  xs[4] = t1.x; xs[5] = t1.y; xs[6] = t1.z; xs[7] = t1.w;
  bf16x8 av = *(const bf16x8*)(attn + (size_t)row * DM_ + lane * 8);
#pragma unroll
  for (int e = 0; e < 8; ++e) as_[e] = (float)av[e];
  float sx = 0, sx2 = 0, sa = 0, sa2 = 0;
#pragma unroll
  for (int e = 0; e < 8; ++e) {
    sx += xs[e]; sx2 += xs[e] * xs[e];
    sa += as_[e]; sa2 += as_[e] * as_[e];
  }
#pragma unroll
  for (int off = 1; off < 64; off <<= 1) {
    sx += __shfl_xor(sx, off);  sx2 += __shfl_xor(sx2, off);
    sa += __shfl_xor(sa, off);  sa2 += __shfl_xor(sa2, off);
  }
  const float inv = 1.f / (float)DM_;
  const float mux = sx * inv, mua = sa * inv;
  const float rx = rsqrtf(fmaxf(sx2 * inv - mux * mux, 0.f) + 1e-5f);
  const float ra = rsqrtf(fmaxf(sa2 * inv - mua * mua, 0.f) + 1e-5f);
  bf16x8 ov;
#pragma unroll
  for (int e = 0; e < 8; ++e) {
    const int c = lane * 8 + e;
    const float val = ((xs[e] - mux) * rx + (as_[e] - mua) * ra) * g1[c] + 2.f * be1[c];
    ov[e] = (bf16)val;
  }
  *(bf16x8*)(out + (size_t)row * DM_ + lane * 8) = ov;
}

// ------------------------------------------------------ final LN residual #2
// out_f32 = x1 + LN(ffn)*g2+be2
__global__ __launch_bounds__(256) void final_ln_kernel(const bf16* __restrict__ x1,
                                                       const bf16* __restrict__ ffn,
                                                       const float* __restrict__ g2,
                                                       const float* __restrict__ be2,
                                                       float* __restrict__ out) {
  const int row = blockIdx.x * 4 + (threadIdx.x >> 6);
  const int lane = threadIdx.x & 63;
  bf16x8 xv = *(const bf16x8*)(x1 + (size_t)row * DM_ + lane * 8);
  bf16x8 fv = *(const bf16x8*)(ffn + (size_t)row * DM_ + lane * 8);
  float fs[8];
#pragma unroll
  for (int e = 0; e < 8; ++e) fs[e] = (float)fv[e];
  float sf = 0, sf2 = 0;
#pragma unroll
  for (int e = 0; e < 8; ++e) { sf += fs[e]; sf2 += fs[e] * fs[e]; }
#pragma unroll
  for (int off = 1; off < 64; off <<= 1) {
    sf += __shfl_xor(sf, off);  sf2 += __shfl_xor(sf2, off);
  }
  const float inv = 1.f / (float)DM_;
  const float mu = sf * inv;
  const float rs = rsqrtf(fmaxf(sf2 * inv - mu * mu, 0.f) + 1e-5f);
  float ov[8];
#pragma unroll
  for (int e = 0; e < 8; ++e) {
    const int c = lane * 8 + e;
    ov[e] = (float)xv[e] + (fs[e] - mu) * rs * g2[c] + be2[c];
  }
  float* orow = out + (size_t)row * DM_ + lane * 8;
  float4 o0 = {ov[0], ov[1], ov[2], ov[3]};
  float4 o1 = {ov[4], ov[5], ov[6], ov[7]};
  ((float4*)orow)[0] = o0;
  ((float4*)orow)[1] = o1;
}

// ---------------------------------------------------------------------------
extern "C" void kernel_launch(void* const* d_in, const int* in_sizes, int n_in,
                              void* d_out, int out_size, void* d_ws, size_t ws_size,
                              hipStream_t stream) {
  const float* x     = (const float*)d_in[0];
  const float* w_qkv = (const float*)d_in[1];
  const float* b_qkv = (const float*)d_in[2];
  const float* w_out = (const float*)d_in[3];
  const float* b_out = (const float*)d_in[4];
  const float* w1    = (const float*)d_in[5];
  const float* b1    = (const float*)d_in[6];
  const float* w2    = (const float*)d_in[7];
  const float* b2    = (const float*)d_in[8];
  const float* g1    = (const float*)d_in[9];
  const float* be1   = (const float*)d_in[10];
  const float* g2    = (const float*)d_in[11];
  const float* be2   = (const float*)d_in[12];
  float* out = (float*)d_out;

  char* ws = (char*)d_ws;
  // workspace layout (bytes), 1KB-aligned blocks
  const size_t o_wqkv = 0;
  const size_t o_wout = o_wqkv + (size_t)DM_ * DM_ * 2;
  const size_t o_w1   = o_wout + (size_t)DM_ * DM_ * 2;
  const size_t o_w2   = o_w1 + (size_t)DFF_ * DM_ * 2;
  const size_t o_A    = o_w2 + (size_t)DM_ * DFF_ * 2;     // x_bf -> ctx_bf
  const size_t o_B    = o_A + (size_t)ROWS_ * DM_ * 2;     // qkv_bf -> x1_bf
  const size_t o_C    = o_B + (size_t)ROWS_ * DM_ * 2;     // attn_bf -> ffn_bf
  const size_t o_D    = o_C + (size_t)ROWS_ * DM_ * 2;     // h1_bf [ROWS,DFF]
  const size_t need   = o_D + (size_t)ROWS_ * DFF_ * 2;
  if (ws_size < need) return;  // would corrupt memory otherwise

  bf16* wqkv_bf = (bf16*)(ws + o_wqkv);
  bf16* wout_bf = (bf16*)(ws + o_wout);
  bf16* w1_bf   = (bf16*)(ws + o_w1);
  bf16* w2_bf   = (bf16*)(ws + o_w2);
  bf16* bufA    = (bf16*)(ws + o_A);
  bf16* bufB    = (bf16*)(ws + o_B);
  bf16* bufC    = (bf16*)(ws + o_C);
  bf16* bufD    = (bf16*)(ws + o_D);

  // 1. converts
  f2b_kernel<<<dim3((ROWS_ * DM_ / 8 + 255) / 256), dim3(256), 0, stream>>>(x, bufA, ROWS_ * DM_ / 8);
  f2b_kernel<<<dim3((DM_ * DM_ / 8 + 255) / 256), dim3(256), 0, stream>>>(w_qkv, wqkv_bf, DM_ * DM_ / 8);
  f2b_kernel<<<dim3((DM_ * DM_ / 8 + 255) / 256), dim3(256), 0, stream>>>(w_out, wout_bf, DM_ * DM_ / 8);
  f2b_kernel<<<dim3((DFF_ * DM_ / 8 + 255) / 256), dim3(256), 0, stream>>>(w1, w1_bf, DFF_ * DM_ / 8);
  f2b_kernel<<<dim3((DM_ * DFF_ / 8 + 255) / 256), dim3(256), 0, stream>>>(w2, w2_bf, DM_ * DFF_ / 8);

  // 2. qkv = x @ w_qkv.T + b_qkv       [16384,512]
  gemm_bt<0><<<dim3(DM_ / 128, ROWS_ / 128), dim3(256), 0, stream>>>(bufA, wqkv_bf, b_qkv, bufB, ROWS_, DM_, DM_);

  // 3. self-attention (Q=K=V=qkv) -> ctx
  attn_kernel<<<dim3(SQ_ / 128, NH_, BN_), dim3(256), 0, stream>>>(bufB, bufA);

  // 4. attn = ctx @ w_out.T + b_out
  gemm_bt<0><<<dim3(DM_ / 128, ROWS_ / 128), dim3(256), 0, stream>>>(bufA, wout_bf, b_out, bufC, ROWS_, DM_, DM_);

  // 5. x1 = LN(x) + LN(attn)
  dual_ln_kernel<<<dim3(ROWS_ / 4), dim3(256), 0, stream>>>(x, bufC, g1, be1, bufB);

  // 6. h1 = relu(x1 @ w1.T + b1)       [16384,2048]
  gemm_bt<1><<<dim3(DFF_ / 128, ROWS_ / 128), dim3(256), 0, stream>>>(bufB, w1_bf, b1, bufD, ROWS_, DFF_, DM_);

  // 7. ffn = h1 @ w2.T + b2            [16384,512]
  gemm_bt<0><<<dim3(DM_ / 128, ROWS_ / 128), dim3(256), 0, stream>>>(bufD, w2_bf, b2, bufC, ROWS_, DM_, DFF_);

  // 8. out = x1 + LN(ffn)
  final_ln_kernel<<<dim3(ROWS_ / 4), dim3(256), 0, stream>>>(bufB, bufC, g2, be2, out);
}

// Round 2
// 276.922 us; speedup vs baseline: 1.4002x; 1.4002x over previous
//
#include <hip/hip_runtime.h>
#include <hip/hip_bf16.h>
#include <stdint.h>

// ---------------------------------------------------------------------------
// EncoderLayer: x[16,1024,512] fp32; all matmuls in bf16 MFMA, fp32 accum.
// ---------------------------------------------------------------------------

using bf16 = __bf16;
typedef __attribute__((ext_vector_type(2))) __bf16 bf16x2;
typedef __attribute__((ext_vector_type(4))) __bf16 bf16x4;
typedef __attribute__((ext_vector_type(8))) __bf16 bf16x8;
typedef __attribute__((ext_vector_type(4))) float floatx4;
typedef __attribute__((ext_vector_type(16))) float f32x16;

#define AS1 __attribute__((address_space(1)))
#define AS3 __attribute__((address_space(3)))

#define L2E 1.44269504088896340736f

constexpr int BN_ = 16, SQ_ = 1024, DM_ = 512, DFF_ = 2048, NH_ = 8, DK_ = 64;
constexpr int ROWS_ = BN_ * SQ_;   // 16384

// ---------------------------------------------------------------- fp32->bf16
__global__ __launch_bounds__(256) void f2b_kernel(const float* __restrict__ in,
                                                  bf16* __restrict__ out, int n8) {
  int i = blockIdx.x * 256 + threadIdx.x;
  if (i >= n8) return;
  float4 a = ((const float4*)in)[2 * i];
  float4 b = ((const float4*)in)[2 * i + 1];
  bf16x8 o;
  o[0] = (bf16)a.x; o[1] = (bf16)a.y; o[2] = (bf16)a.z; o[3] = (bf16)a.w;
  o[4] = (bf16)b.x; o[5] = (bf16)b.y; o[6] = (bf16)b.z; o[7] = (bf16)b.w;
  ((bf16x8*)out)[i] = o;
}

// ------------------------------------------------------------------- GEMM
// C[M,N] = A[M,K] @ B[N,K]^T + bias, optional ReLU, bf16 out. (unchanged)
template <int RELU>
__global__ __launch_bounds__(256) void gemm_bt(const bf16* __restrict__ A,
                                               const bf16* __restrict__ B,
                                               const float* __restrict__ bias,
                                               bf16* __restrict__ C,
                                               int M, int N, int K) {
  __shared__ bf16 As[128 * 32];
  __shared__ bf16 Bs[128 * 32];
  const int tid = threadIdx.x;
  const int lane = tid & 63;
  const int wv = tid >> 6;
  const int wr = wv >> 1, wc = wv & 1;
  const int r15 = lane & 15, g = lane >> 4;
  const int tileN = blockIdx.x * 128;
  const int tileM = blockIdx.y * 128;

  floatx4 acc[4][4] = {};

  const int nk = K >> 5;
  for (int kt = 0; kt < nk; ++kt) {
    const int k0 = kt << 5;
    __syncthreads();
#pragma unroll
    for (int is = 0; is < 2; ++is) {
      const int base = wv * 2048 + is * 1024;
      const int ob = base + lane * 16;
      const int row = ob >> 6;
      const int pslot = (ob >> 4) & 3;
      const int sslot = pslot ^ ((row >> 1) & 3);
      const bf16* ga = A + (size_t)(tileM + row) * K + (k0 + sslot * 8);
      __builtin_amdgcn_global_load_lds((AS1 uint32_t*)ga,
                                       (AS3 uint32_t*)((AS3 char*)As + base),
                                       16, 0, 0);
      const bf16* gb = B + (size_t)(tileN + row) * K + (k0 + sslot * 8);
      __builtin_amdgcn_global_load_lds((AS1 uint32_t*)gb,
                                       (AS3 uint32_t*)((AS3 char*)Bs + base),
                                       16, 0, 0);
    }
    __syncthreads();

    bf16x8 af[4], bfr[4];
#pragma unroll
    for (int m = 0; m < 4; ++m) {
      const int arow = wr * 64 + m * 16 + r15;
      const int ab = (arow * 64 + g * 16) ^ (((arow >> 1) & 3) << 4);
      af[m] = *(const bf16x8*)((const char*)As + ab);
    }
#pragma unroll
    for (int n = 0; n < 4; ++n) {
      const int brow = wc * 64 + n * 16 + r15;
      const int bb = (brow * 64 + g * 16) ^ (((brow >> 1) & 3) << 4);
      bfr[n] = *(const bf16x8*)((const char*)Bs + bb);
    }
#pragma unroll
    for (int m = 0; m < 4; ++m)
#pragma unroll
      for (int n = 0; n < 4; ++n)
        acc[m][n] = __builtin_amdgcn_mfma_f32_16x16x32_bf16(af[m], bfr[n],
                                                            acc[m][n], 0, 0, 0);
  }

#pragma unroll
  for (int n = 0; n < 4; ++n) {
    const int col = tileN + wc * 64 + n * 16 + r15;
    const float bv = bias[col];
#pragma unroll
    for (int m = 0; m < 4; ++m) {
      const int row0 = tileM + wr * 64 + m * 16 + g * 4;
#pragma unroll
      for (int j = 0; j < 4; ++j) {
        float v = acc[m][n][j] + bv;
        if (RELU) v = fmaxf(v, 0.f);
        C[(size_t)(row0 + j) * N + col] = (bf16)v;
      }
    }
  }
}

// ----------------------------------------------------------- flash attention
// Q = K = V = qkv[b,:,h*64:(h+1)*64].  One block = 128 q-rows of one (b,h).
// 4 waves x 32 q-rows, KVBLK=64, 32x32x16 MFMA, swapped operands:
//   S^T[s,q] = mfma(K_rows, Q_rows)  -> lane owns one q column (q = lane&31)
//   softmax fully in-register (1 shfl_xor(32) per reduction)
//   P stays in registers; PV B-frag built via bf16 packing + shfl_xor(32)
//   PV A-frag = V columns read from the SAME staged K tile via ds_read_b64_tr_b16
// LDS: one 8KB subtiled tile [ssub=s/4][dsub=d/16][4][16] staged by
// global_load_lds(16B) with pre-permuted global source (linear LDS dest).
__global__ __launch_bounds__(256) void attn_kernel(const bf16* __restrict__ qkv,
                                                   bf16* __restrict__ ctx) {
  __shared__ char lds[16384];   // loop: first 8KB = K tile; epilogue: 4KB/wave

  const int tid = threadIdx.x;
  const int lane = tid & 63;
  const int wv = tid >> 6;
  const int l31 = lane & 31;
  const int h = lane >> 5;                 // k-half for 32x32x16 operands
  const int b = blockIdx.z, hd = blockIdx.y, qt = blockIdx.x;
  const size_t headoff = (size_t)b * SQ_ * DM_ + hd * DK_;
  const int q0 = qt * 128 + wv * 32;

  // ---- Q fragments (B operand): Q[q=l31][d = 16*kd + 8*h + e] * 0.125
  bf16x8 aq[4];
#pragma unroll
  for (int kd = 0; kd < 4; ++kd) {
    const bf16* gq = qkv + headoff + (size_t)(q0 + l31) * DM_ + kd * 16 + h * 8;
    bf16x8 v = *(const bf16x8*)gq;
#pragma unroll
    for (int e = 0; e < 8; ++e) v[e] = (bf16)((float)v[e] * 0.125f);
    aq[kd] = v;
  }

  f32x16 o0 = {}, o1 = {};                 // Ot[d,q]: df=0,1 (d-halves)
  float mstate = -1e30f, lstate = 0.f;

  const uint32_t ldsb = (uint32_t)(uintptr_t)(AS3 char*)lds;

  for (int kt = 0; kt < SQ_ / 64; ++kt) {
    __syncthreads();
    // ---- stage K tile (subtiled layout, linear LDS dest, permuted source)
#pragma unroll
    for (int is = 0; is < 2; ++is) {
      const int ob = is * 4096 + wv * 1024 + lane * 16;   // dest byte (w/ lane)
      const int e0 = ob >> 1;                              // dest elem
      const int srow = kt * 64 + ((e0 >> 8) << 2) + ((e0 >> 4) & 3);
      const int dcol = ((e0 >> 6) & 3) * 16 + ((e0 >> 3) & 1) * 8;
      const bf16* src = qkv + headoff + (size_t)srow * DM_ + dcol;
      __builtin_amdgcn_global_load_lds((AS1 uint32_t*)src,
                                       (AS3 uint32_t*)((AS3 char*)lds + is * 4096 + wv * 1024),
                                       16, 0, 0);
    }
    __syncthreads();

    // ---- S^T = K · Q^T : A = K rows (from subtiled tile), B = aq
    f32x16 s0v = {}, s1v = {};
    const char* pabase = (const char*)lds + (l31 >> 2) * 512 + (l31 & 3) * 32 + h * 16;
    __builtin_amdgcn_s_setprio(1);
#pragma unroll
    for (int kd = 0; kd < 4; ++kd) {
      bf16x8 a0 = *(const bf16x8*)(pabase + kd * 128);
      bf16x8 a1 = *(const bf16x8*)(pabase + kd * 128 + 4096);
      s0v = __builtin_amdgcn_mfma_f32_32x32x16_bf16(a0, aq[kd], s0v, 0, 0, 0);
      s1v = __builtin_amdgcn_mfma_f32_32x32x16_bf16(a1, aq[kd], s1v, 0, 0, 0);
    }
    __builtin_amdgcn_s_setprio(0);

    // ---- online softmax over s (lane owns q = l31; partner lane has other s half)
    float mx = s0v[0];
#pragma unroll
    for (int r = 1; r < 16; ++r) mx = fmaxf(mx, s0v[r]);
#pragma unroll
    for (int r = 0; r < 16; ++r) mx = fmaxf(mx, s1v[r]);
    mx = fmaxf(mx, __shfl_xor(mx, 32));
    const float nm = fmaxf(mstate, mx);
    const float al = exp2f((mstate - nm) * L2E);
    mstate = nm;
    float rs = 0.f;
#pragma unroll
    for (int r = 0; r < 16; ++r) {
      float p = exp2f((s0v[r] - nm) * L2E);
      s0v[r] = p; rs += p;
    }
#pragma unroll
    for (int r = 0; r < 16; ++r) {
      float p = exp2f((s1v[r] - nm) * L2E);
      s1v[r] = p; rs += p;
    }
    rs += __shfl_xor(rs, 32);
    lstate = lstate * al + rs;
#pragma unroll
    for (int r = 0; r < 16; ++r) { o0[r] *= al; o1[r] *= al; }

    // ---- build PV B-fragments (P^T[s][q=l31]) in registers
    // source regs: s = 16*ks + 4*h_src + (X&3) + 8*(X>>2), X = 8*(ks&1)+x
    uint32_t pf[4][4];
#pragma unroll
    for (int ks = 0; ks < 4; ++ks) {
      const int kb = (ks & 1) * 8;
      float v0, v1, v2, v3, v4, v5, v6, v7;
      if (ks < 2) {
        v0 = s0v[kb+0]; v1 = s0v[kb+1]; v2 = s0v[kb+2]; v3 = s0v[kb+3];
        v4 = s0v[kb+4]; v5 = s0v[kb+5]; v6 = s0v[kb+6]; v7 = s0v[kb+7];
      } else {
        v0 = s1v[kb+0]; v1 = s1v[kb+1]; v2 = s1v[kb+2]; v3 = s1v[kb+3];
        v4 = s1v[kb+4]; v5 = s1v[kb+5]; v6 = s1v[kb+6]; v7 = s1v[kb+7];
      }
      union { bf16x2 v; uint32_t u; } P0, P1, P2, P3;
      P0.v = bf16x2{(bf16)v0, (bf16)v1};
      P1.v = bf16x2{(bf16)v2, (bf16)v3};
      P2.v = bf16x2{(bf16)v4, (bf16)v5};
      P3.v = bf16x2{(bf16)v6, (bf16)v7};
      const uint32_t S0 = (uint32_t)__shfl_xor((int)P0.u, 32);
      const uint32_t S1 = (uint32_t)__shfl_xor((int)P1.u, 32);
      const uint32_t S2 = (uint32_t)__shfl_xor((int)P2.u, 32);
      const uint32_t S3 = (uint32_t)__shfl_xor((int)P3.u, 32);
      pf[ks][0] = h ? S2 : P0.u;
      pf[ks][1] = h ? S3 : P1.u;
      pf[ks][2] = h ? P2.u : S0;
      pf[ks][3] = h ? P3.u : S1;
    }

    // ---- PV: Ot[d,q] += V^T-rows (tr-read) x P^T
#pragma unroll
    for (int df = 0; df < 2; ++df) {
      const uint32_t vb = ldsb + df * 256 + (lane & 15) * 8 +
                          ((lane >> 4) & 1) * 128 + (lane >> 5) * 1024;
      bf16x4 lo[4], hi[4];
#pragma unroll
      for (int ks = 0; ks < 4; ++ks) {
        asm volatile("ds_read_b64_tr_b16 %0, %2\n\t"
                     "ds_read_b64_tr_b16 %1, %2 offset:512"
                     : "=&v"(lo[ks]), "=&v"(hi[ks])
                     : "v"(vb + ks * 2048));
      }
      asm volatile("s_waitcnt lgkmcnt(0)" ::: "memory");
      __builtin_amdgcn_sched_barrier(0);
      __builtin_amdgcn_s_setprio(1);
#pragma unroll
      for (int ks = 0; ks < 4; ++ks) {
        union { struct { bf16x4 l, h; } p; bf16x8 v; } av;
        av.p.l = lo[ks]; av.p.h = hi[ks];
        union { uint32_t u[4]; bf16x8 v; } bv;
        bv.u[0] = pf[ks][0]; bv.u[1] = pf[ks][1];
        bv.u[2] = pf[ks][2]; bv.u[3] = pf[ks][3];
        if (df == 0)
          o0 = __builtin_amdgcn_mfma_f32_32x32x16_bf16(av.v, bv.v, o0, 0, 0, 0);
        else
          o1 = __builtin_amdgcn_mfma_f32_32x32x16_bf16(av.v, bv.v, o1, 0, 0, 0);
      }
      __builtin_amdgcn_s_setprio(0);
    }
  }

  // ---- epilogue: normalize, per-wave LDS transpose, coalesced store
  __syncthreads();   // done with K tile region
  const float invl = 1.f / lstate;
  char* wb = (char*)lds + wv * 4096;   // [q=32][d=64] bf16, XOR-swizzled rows
#pragma unroll
  for (int df = 0; df < 2; ++df)
#pragma unroll
    for (int t = 0; t < 4; ++t) {
      const f32x16& ov = df ? o1 : o0;
      bf16x4 pkt;
      pkt[0] = (bf16)(ov[4*t+0] * invl);
      pkt[1] = (bf16)(ov[4*t+1] * invl);
      pkt[2] = (bf16)(ov[4*t+2] * invl);
      pkt[3] = (bf16)(ov[4*t+3] * invl);
      const int byte = (l31 * 128 + df * 64 + t * 16 + h * 8) ^ ((l31 & 7) << 4);
      *(bf16x4*)(wb + byte) = pkt;
    }
  // same-wave read-back (no barrier needed), coalesced global store
#pragma unroll
  for (int ps = 0; ps < 4; ++ps) {
    const int qr = ps * 8 + (lane >> 3);
    const int byte = (qr * 128 + (lane & 7) * 16) ^ ((qr & 7) << 4);
    bf16x8 vv = *(const bf16x8*)(wb + byte);
    bf16* dst = ctx + (size_t)(b * SQ_ + q0 + qr) * DM_ + hd * 64 + (lane & 7) * 8;
    *(bf16x8*)dst = vv;
  }
}

// ------------------------------------------------- dual LayerNorm residual #1
__global__ __launch_bounds__(256) void dual_ln_kernel(const float* __restrict__ x,
                                                      const bf16* __restrict__ attn,
                                                      const float* __restrict__ g1,
                                                      const float* __restrict__ be1,
                                                      bf16* __restrict__ out) {
  const int row = blockIdx.x * 4 + (threadIdx.x >> 6);
  const int lane = threadIdx.x & 63;
  const float* xr = x + (size_t)row * DM_ + lane * 8;
  float xs[8], as_[8];
  float4 t0 = ((const float4*)xr)[0];
  float4 t1 = ((const float4*)xr)[1];
  xs[0] = t0.x; xs[1] = t0.y; xs[2] = t0.z; xs[3] = t0.w;
  xs[4] = t1.x; xs[5] = t1.y; xs[6] = t1.z; xs[7] = t1.w;
  bf16x8 av = *(const bf16x8*)(attn + (size_t)row * DM_ + lane * 8);
#pragma unroll
  for (int e = 0; e < 8; ++e) as_[e] = (float)av[e];
  float sx = 0, sx2 = 0, sa = 0, sa2 = 0;
#pragma unroll
  for (int e = 0; e < 8; ++e) {
    sx += xs[e]; sx2 += xs[e] * xs[e];
    sa += as_[e]; sa2 += as_[e] * as_[e];
  }
#pragma unroll
  for (int off = 1; off < 64; off <<= 1) {
    sx += __shfl_xor(sx, off);  sx2 += __shfl_xor(sx2, off);
    sa += __shfl_xor(sa, off);  sa2 += __shfl_xor(sa2, off);
  }
  const float inv = 1.f / (float)DM_;
  const float mux = sx * inv, mua = sa * inv;
  const float rx = rsqrtf(fmaxf(sx2 * inv - mux * mux, 0.f) + 1e-5f);
  const float ra = rsqrtf(fmaxf(sa2 * inv - mua * mua, 0.f) + 1e-5f);
  bf16x8 ov;
#pragma unroll
  for (int e = 0; e < 8; ++e) {
    const int c = lane * 8 + e;
    const float val = ((xs[e] - mux) * rx + (as_[e] - mua) * ra) * g1[c] + 2.f * be1[c];
    ov[e] = (bf16)val;
  }
  *(bf16x8*)(out + (size_t)row * DM_ + lane * 8) = ov;
}

// ------------------------------------------------------ final LN residual #2
__global__ __launch_bounds__(256) void final_ln_kernel(const bf16* __restrict__ x1,
                                                       const bf16* __restrict__ ffn,
                                                       const float* __restrict__ g2,
                                                       const float* __restrict__ be2,
                                                       float* __restrict__ out) {
  const int row = blockIdx.x * 4 + (threadIdx.x >> 6);
  const int lane = threadIdx.x & 63;
  bf16x8 xv = *(const bf16x8*)(x1 + (size_t)row * DM_ + lane * 8);
  bf16x8 fv = *(const bf16x8*)(ffn + (size_t)row * DM_ + lane * 8);
  float fs[8];
#pragma unroll
  for (int e = 0; e < 8; ++e) fs[e] = (float)fv[e];
  float sf = 0, sf2 = 0;
#pragma unroll
  for (int e = 0; e < 8; ++e) { sf += fs[e]; sf2 += fs[e] * fs[e]; }
#pragma unroll
  for (int off = 1; off < 64; off <<= 1) {
    sf += __shfl_xor(sf, off);  sf2 += __shfl_xor(sf2, off);
  }
  const float inv = 1.f / (float)DM_;
  const float mu = sf * inv;
  const float rs = rsqrtf(fmaxf(sf2 * inv - mu * mu, 0.f) + 1e-5f);
  float ov[8];
#pragma unroll
  for (int e = 0; e < 8; ++e) {
    const int c = lane * 8 + e;
    ov[e] = (float)xv[e] + (fs[e] - mu) * rs * g2[c] + be2[c];
  }
  float* orow = out + (size_t)row * DM_ + lane * 8;
  float4 o0 = {ov[0], ov[1], ov[2], ov[3]};
  float4 o1 = {ov[4], ov[5], ov[6], ov[7]};
  ((float4*)orow)[0] = o0;
  ((float4*)orow)[1] = o1;
}

// ---------------------------------------------------------------------------
extern "C" void kernel_launch(void* const* d_in, const int* in_sizes, int n_in,
                              void* d_out, int out_size, void* d_ws, size_t ws_size,
                              hipStream_t stream) {
  const float* x     = (const float*)d_in[0];
  const float* w_qkv = (const float*)d_in[1];
  const float* b_qkv = (const float*)d_in[2];
  const float* w_out = (const float*)d_in[3];
  const float* b_out = (const float*)d_in[4];
  const float* w1    = (const float*)d_in[5];
  const float* b1    = (const float*)d_in[6];
  const float* w2    = (const float*)d_in[7];
  const float* b2    = (const float*)d_in[8];
  const float* g1    = (const float*)d_in[9];
  const float* be1   = (const float*)d_in[10];
  const float* g2    = (const float*)d_in[11];
  const float* be2   = (const float*)d_in[12];
  float* out = (float*)d_out;

  char* ws = (char*)d_ws;
  const size_t o_wqkv = 0;
  const size_t o_wout = o_wqkv + (size_t)DM_ * DM_ * 2;
  const size_t o_w1   = o_wout + (size_t)DM_ * DM_ * 2;
  const size_t o_w2   = o_w1 + (size_t)DFF_ * DM_ * 2;
  const size_t o_A    = o_w2 + (size_t)DM_ * DFF_ * 2;     // x_bf -> ctx_bf
  const size_t o_B    = o_A + (size_t)ROWS_ * DM_ * 2;     // qkv_bf -> x1_bf
  const size_t o_C    = o_B + (size_t)ROWS_ * DM_ * 2;     // attn_bf -> ffn_bf
  const size_t o_D    = o_C + (size_t)ROWS_ * DM_ * 2;     // h1_bf [ROWS,DFF]
  const size_t need   = o_D + (size_t)ROWS_ * DFF_ * 2;
  if (ws_size < need) return;

  bf16* wqkv_bf = (bf16*)(ws + o_wqkv);
  bf16* wout_bf = (bf16*)(ws + o_wout);
  bf16* w1_bf   = (bf16*)(ws + o_w1);
  bf16* w2_bf   = (bf16*)(ws + o_w2);
  bf16* bufA    = (bf16*)(ws + o_A);
  bf16* bufB    = (bf16*)(ws + o_B);
  bf16* bufC    = (bf16*)(ws + o_C);
  bf16* bufD    = (bf16*)(ws + o_D);

  // 1. converts
  f2b_kernel<<<dim3((ROWS_ * DM_ / 8 + 255) / 256), dim3(256), 0, stream>>>(x, bufA, ROWS_ * DM_ / 8);
  f2b_kernel<<<dim3((DM_ * DM_ / 8 + 255) / 256), dim3(256), 0, stream>>>(w_qkv, wqkv_bf, DM_ * DM_ / 8);
  f2b_kernel<<<dim3((DM_ * DM_ / 8 + 255) / 256), dim3(256), 0, stream>>>(w_out, wout_bf, DM_ * DM_ / 8);
  f2b_kernel<<<dim3((DFF_ * DM_ / 8 + 255) / 256), dim3(256), 0, stream>>>(w1, w1_bf, DFF_ * DM_ / 8);
  f2b_kernel<<<dim3((DM_ * DFF_ / 8 + 255) / 256), dim3(256), 0, stream>>>(w2, w2_bf, DM_ * DFF_ / 8);

  // 2. qkv = x @ w_qkv.T + b_qkv       [16384,512]
  gemm_bt<0><<<dim3(DM_ / 128, ROWS_ / 128), dim3(256), 0, stream>>>(bufA, wqkv_bf, b_qkv, bufB, ROWS_, DM_, DM_);

  // 3. self-attention (Q=K=V=qkv) -> ctx
  attn_kernel<<<dim3(SQ_ / 128, NH_, BN_), dim3(256), 0, stream>>>(bufB, bufA);

  // 4. attn = ctx @ w_out.T + b_out
  gemm_bt<0><<<dim3(DM_ / 128, ROWS_ / 128), dim3(256), 0, stream>>>(bufA, wout_bf, b_out, bufC, ROWS_, DM_, DM_);

  // 5. x1 = LN(x) + LN(attn)
  dual_ln_kernel<<<dim3(ROWS_ / 4), dim3(256), 0, stream>>>(x, bufC, g1, be1, bufB);

  // 6. h1 = relu(x1 @ w1.T + b1)       [16384,2048]
  gemm_bt<1><<<dim3(DFF_ / 128, ROWS_ / 128), dim3(256), 0, stream>>>(bufB, w1_bf, b1, bufD, ROWS_, DFF_, DM_);

  // 7. ffn = h1 @ w2.T + b2            [16384,512]
  gemm_bt<0><<<dim3(DM_ / 128, ROWS_ / 128), dim3(256), 0, stream>>>(bufD, w2_bf, b2, bufC, ROWS_, DM_, DFF_);

  // 8. out = x1 + LN(ffn)
  final_ln_kernel<<<dim3(ROWS_ / 4), dim3(256), 0, stream>>>(bufB, bufC, g2, be2, out);
}

// Round 3
// 259.639 us; speedup vs baseline: 1.4934x; 1.0666x over previous
//
#include <hip/hip_runtime.h>
#include <hip/hip_bf16.h>
#include <stdint.h>

// ---------------------------------------------------------------------------
// EncoderLayer: x[16,1024,512] fp32; all matmuls in bf16 MFMA, fp32 accum.
// ---------------------------------------------------------------------------

using bf16 = __bf16;
typedef __attribute__((ext_vector_type(2))) __bf16 bf16x2;
typedef __attribute__((ext_vector_type(4))) __bf16 bf16x4;
typedef __attribute__((ext_vector_type(8))) __bf16 bf16x8;
typedef __attribute__((ext_vector_type(4))) float floatx4;
typedef __attribute__((ext_vector_type(16))) float f32x16;

#define AS1 __attribute__((address_space(1)))
#define AS3 __attribute__((address_space(3)))

#define L2E 1.44269504088896340736f

constexpr int BN_ = 16, SQ_ = 1024, DM_ = 512, DFF_ = 2048, NH_ = 8, DK_ = 64;
constexpr int ROWS_ = BN_ * SQ_;   // 16384

// ---------------------------------------------------------------- fp32->bf16
__global__ __launch_bounds__(256) void f2b_kernel(const float* __restrict__ in,
                                                  bf16* __restrict__ out, int n8) {
  int i = blockIdx.x * 256 + threadIdx.x;
  if (i >= n8) return;
  float4 a = ((const float4*)in)[2 * i];
  float4 b = ((const float4*)in)[2 * i + 1];
  bf16x8 o;
  o[0] = (bf16)a.x; o[1] = (bf16)a.y; o[2] = (bf16)a.z; o[3] = (bf16)a.w;
  o[4] = (bf16)b.x; o[5] = (bf16)b.y; o[6] = (bf16)b.z; o[7] = (bf16)b.w;
  ((bf16x8*)out)[i] = o;
}

// ------------------------------------------------------------------- GEMM
// C[M,N] = A[M,K] @ B[N,K]^T + bias, optional ReLU, bf16 out. (unchanged)
template <int RELU>
__global__ __launch_bounds__(256) void gemm_bt(const bf16* __restrict__ A,
                                               const bf16* __restrict__ B,
                                               const float* __restrict__ bias,
                                               bf16* __restrict__ C,
                                               int M, int N, int K) {
  __shared__ bf16 As[128 * 32];
  __shared__ bf16 Bs[128 * 32];
  const int tid = threadIdx.x;
  const int lane = tid & 63;
  const int wv = tid >> 6;
  const int wr = wv >> 1, wc = wv & 1;
  const int r15 = lane & 15, g = lane >> 4;
  const int tileN = blockIdx.x * 128;
  const int tileM = blockIdx.y * 128;

  floatx4 acc[4][4] = {};

  const int nk = K >> 5;
  for (int kt = 0; kt < nk; ++kt) {
    const int k0 = kt << 5;
    __syncthreads();
#pragma unroll
    for (int is = 0; is < 2; ++is) {
      const int base = wv * 2048 + is * 1024;
      const int ob = base + lane * 16;
      const int row = ob >> 6;
      const int pslot = (ob >> 4) & 3;
      const int sslot = pslot ^ ((row >> 1) & 3);
      const bf16* ga = A + (size_t)(tileM + row) * K + (k0 + sslot * 8);
      __builtin_amdgcn_global_load_lds((AS1 uint32_t*)ga,
                                       (AS3 uint32_t*)((AS3 char*)As + base),
                                       16, 0, 0);
      const bf16* gb = B + (size_t)(tileN + row) * K + (k0 + sslot * 8);
      __builtin_amdgcn_global_load_lds((AS1 uint32_t*)gb,
                                       (AS3 uint32_t*)((AS3 char*)Bs + base),
                                       16, 0, 0);
    }
    __syncthreads();

    bf16x8 af[4], bfr[4];
#pragma unroll
    for (int m = 0; m < 4; ++m) {
      const int arow = wr * 64 + m * 16 + r15;
      const int ab = (arow * 64 + g * 16) ^ (((arow >> 1) & 3) << 4);
      af[m] = *(const bf16x8*)((const char*)As + ab);
    }
#pragma unroll
    for (int n = 0; n < 4; ++n) {
      const int brow = wc * 64 + n * 16 + r15;
      const int bb = (brow * 64 + g * 16) ^ (((brow >> 1) & 3) << 4);
      bfr[n] = *(const bf16x8*)((const char*)Bs + bb);
    }
#pragma unroll
    for (int m = 0; m < 4; ++m)
#pragma unroll
      for (int n = 0; n < 4; ++n)
        acc[m][n] = __builtin_amdgcn_mfma_f32_16x16x32_bf16(af[m], bfr[n],
                                                            acc[m][n], 0, 0, 0);
  }

#pragma unroll
  for (int n = 0; n < 4; ++n) {
    const int col = tileN + wc * 64 + n * 16 + r15;
    const float bv = bias[col];
#pragma unroll
    for (int m = 0; m < 4; ++m) {
      const int row0 = tileM + wr * 64 + m * 16 + g * 4;
#pragma unroll
      for (int j = 0; j < 4; ++j) {
        float v = acc[m][n][j] + bv;
        if (RELU) v = fmaxf(v, 0.f);
        C[(size_t)(row0 + j) * N + col] = (bf16)v;
      }
    }
  }
}

// ----------------------------------------------------------- flash attention
// Q = K = V = qkv[b,:,h*64:(h+1)*64].  One block = 128 q-rows of one (b,h).
// 4 waves x 32 q-rows, KVBLK=64, 32x32x16 MFMA, swapped operands.
// This round: log2-domain softmax (L2E folded into Q scale), permlane32_swap
// P-pack, defer-max (THR=8 log2 units), double-buffered K tile with counted
// vmcnt + raw s_barrier (stage t+1 overlaps compute of t).
__global__ __launch_bounds__(256) void attn_kernel(const bf16* __restrict__ qkv,
                                                   bf16* __restrict__ ctx) {
  __shared__ char lds[16384];   // 2 x 8KB K-tile double buffer; epilogue reuses

  const int tid = threadIdx.x;
  const int lane = tid & 63;
  const int wv = tid >> 6;
  const int l31 = lane & 31;
  const int h = lane >> 5;                 // k-half for 32x32x16 operands
  const int b = blockIdx.z, hd = blockIdx.y, qt = blockIdx.x;
  const size_t headoff = (size_t)b * SQ_ * DM_ + hd * DK_;
  const int q0 = qt * 128 + wv * 32;

  // ---- Q fragments (B operand): Q[q=l31][d=16*kd+8*h+e] * (0.125 * log2 e)
  const float QS = 0.125f * L2E;
  bf16x8 aq[4];
#pragma unroll
  for (int kd = 0; kd < 4; ++kd) {
    const bf16* gq = qkv + headoff + (size_t)(q0 + l31) * DM_ + kd * 16 + h * 8;
    bf16x8 v = *(const bf16x8*)gq;
#pragma unroll
    for (int e = 0; e < 8; ++e) v[e] = (bf16)((float)v[e] * QS);
    aq[kd] = v;
  }

  f32x16 o0 = {}, o1 = {};                 // Ot[d,q]: df=0,1 (d-halves)
  float mstate = -1e30f, lstate = 0.f;

  const uint32_t ldsb = (uint32_t)(uintptr_t)(AS3 char*)lds;

  // ---- staging address precompute (tile-relative; subtiled layout)
  // dest elem e0 -> srow = (e0>>8)*4 + ((e0>>4)&3), dcol = ((e0>>6)&3)*16 + ((e0>>3)&1)*8
  uint32_t dstoff[2];
  const bf16* srcb[2];
#pragma unroll
  for (int is = 0; is < 2; ++is) {
    const int ob = is * 4096 + wv * 1024 + lane * 16;
    const int e0 = ob >> 1;
    const int srow = ((e0 >> 8) << 2) + ((e0 >> 4) & 3);
    const int dcol = ((e0 >> 6) & 3) * 16 + ((e0 >> 3) & 1) * 8;
    dstoff[is] = is * 4096 + wv * 1024;    // wave-uniform LDS base
    srcb[is] = qkv + headoff + (size_t)srow * DM_ + dcol;
  }

#define STAGE(buf, t)                                                          \
  {                                                                            \
    _Pragma("unroll")                                                          \
    for (int is = 0; is < 2; ++is) {                                           \
      __builtin_amdgcn_global_load_lds(                                        \
          (AS1 uint32_t*)(srcb[is] + (size_t)(t) * 64 * DM_),                  \
          (AS3 uint32_t*)((AS3 char*)lds + (buf) * 8192 + dstoff[is]), 16, 0, 0); \
    }                                                                          \
  }

  constexpr int NT = SQ_ / 64;   // 16
  STAGE(0, 0);

  for (int t = 0; t < NT; ++t) {
    const int cur = t & 1;
    // barrier #1: all waves done reading buf[cur^1] (iter t-1) -> safe to overwrite
    __builtin_amdgcn_s_barrier();
    if (t + 1 < NT) {
      STAGE(cur ^ 1, t + 1);
      asm volatile("s_waitcnt vmcnt(2)" ::: "memory");   // tile t's 2 loads done
    } else {
      asm volatile("s_waitcnt vmcnt(0)" ::: "memory");
    }
    // barrier #2: all waves' stage of buf[cur] visible
    __builtin_amdgcn_s_barrier();
    __builtin_amdgcn_sched_barrier(0);

    const char* tile = (const char*)lds + cur * 8192;

    // ---- S^T = K · Q^T (log2 domain): A = K rows (subtiled), B = aq
    f32x16 s0v = {}, s1v = {};
    const char* pabase = tile + (l31 >> 2) * 512 + (l31 & 3) * 32 + h * 16;
    __builtin_amdgcn_s_setprio(1);
#pragma unroll
    for (int kd = 0; kd < 4; ++kd) {
      bf16x8 a0 = *(const bf16x8*)(pabase + kd * 128);
      bf16x8 a1 = *(const bf16x8*)(pabase + kd * 128 + 4096);
      s0v = __builtin_amdgcn_mfma_f32_32x32x16_bf16(a0, aq[kd], s0v, 0, 0, 0);
      s1v = __builtin_amdgcn_mfma_f32_32x32x16_bf16(a1, aq[kd], s1v, 0, 0, 0);
    }
    __builtin_amdgcn_s_setprio(0);

    // ---- online softmax, log2 domain; lane owns q = l31
    float mx = s0v[0];
#pragma unroll
    for (int r = 1; r < 16; ++r) mx = fmaxf(mx, s0v[r]);
#pragma unroll
    for (int r = 0; r < 16; ++r) mx = fmaxf(mx, s1v[r]);
    mx = fmaxf(mx, __shfl_xor(mx, 32));
    // defer-max (T13): only rescale when max grew by > 8 (log2 units)
    if (!__all(mx - mstate <= 8.f)) {
      const float nm = fmaxf(mstate, mx);
      const float al = exp2f(mstate - nm);
      mstate = nm;
      lstate *= al;
#pragma unroll
      for (int r = 0; r < 16; ++r) { o0[r] *= al; o1[r] *= al; }
    }
    float rs = 0.f;
#pragma unroll
    for (int r = 0; r < 16; ++r) {
      float p = exp2f(s0v[r] - mstate);
      s0v[r] = p; rs += p;
    }
#pragma unroll
    for (int r = 0; r < 16; ++r) {
      float p = exp2f(s1v[r] - mstate);
      s1v[r] = p; rs += p;
    }
    rs += __shfl_xor(rs, 32);
    lstate += rs;

    // ---- build PV B-fragments in registers: cvt_pk pairs + permlane32_swap
    uint32_t pf[4][4];
#pragma unroll
    for (int ks = 0; ks < 4; ++ks) {
      const int kb = (ks & 1) * 8;
      float v0, v1, v2, v3, v4, v5, v6, v7;
      if (ks < 2) {
        v0 = s0v[kb+0]; v1 = s0v[kb+1]; v2 = s0v[kb+2]; v3 = s0v[kb+3];
        v4 = s0v[kb+4]; v5 = s0v[kb+5]; v6 = s0v[kb+6]; v7 = s0v[kb+7];
      } else {
        v0 = s1v[kb+0]; v1 = s1v[kb+1]; v2 = s1v[kb+2]; v3 = s1v[kb+3];
        v4 = s1v[kb+4]; v5 = s1v[kb+5]; v6 = s1v[kb+6]; v7 = s1v[kb+7];
      }
      union { bf16x2 v; uint32_t u; } P0, P1, P2, P3;
      P0.v = bf16x2{(bf16)v0, (bf16)v1};
      P1.v = bf16x2{(bf16)v2, (bf16)v3};
      P2.v = bf16x2{(bf16)v4, (bf16)v5};
      P3.v = bf16x2{(bf16)v6, (bf16)v7};
      // swap(P0,P2): P0 <- pf[0], P2 <- pf[2]; swap(P1,P3): pf[1], pf[3]
      asm volatile("v_permlane32_swap_b32 %0, %1" : "+v"(P0.u), "+v"(P2.u));
      asm volatile("v_permlane32_swap_b32 %0, %1" : "+v"(P1.u), "+v"(P3.u));
      pf[ks][0] = P0.u;
      pf[ks][1] = P1.u;
      pf[ks][2] = P2.u;
      pf[ks][3] = P3.u;
    }

    // ---- PV: Ot[d,q] += V^T-rows (tr-read) x P^T
#pragma unroll
    for (int df = 0; df < 2; ++df) {
      const uint32_t vb = ldsb + cur * 8192 + df * 256 + (lane & 15) * 8 +
                          ((lane >> 4) & 1) * 128 + (lane >> 5) * 1024;
      bf16x4 lo[4], hi[4];
#pragma unroll
      for (int ks = 0; ks < 4; ++ks) {
        asm volatile("ds_read_b64_tr_b16 %0, %2\n\t"
                     "ds_read_b64_tr_b16 %1, %2 offset:512"
                     : "=&v"(lo[ks]), "=&v"(hi[ks])
                     : "v"(vb + ks * 2048));
      }
      asm volatile("s_waitcnt lgkmcnt(0)" ::: "memory");
      __builtin_amdgcn_sched_barrier(0);
      __builtin_amdgcn_s_setprio(1);
#pragma unroll
      for (int ks = 0; ks < 4; ++ks) {
        union { struct { bf16x4 l, h; } p; bf16x8 v; } av;
        av.p.l = lo[ks]; av.p.h = hi[ks];
        union { uint32_t u[4]; bf16x8 v; } bv;
        bv.u[0] = pf[ks][0]; bv.u[1] = pf[ks][1];
        bv.u[2] = pf[ks][2]; bv.u[3] = pf[ks][3];
        if (df == 0)
          o0 = __builtin_amdgcn_mfma_f32_32x32x16_bf16(av.v, bv.v, o0, 0, 0, 0);
        else
          o1 = __builtin_amdgcn_mfma_f32_32x32x16_bf16(av.v, bv.v, o1, 0, 0, 0);
      }
      __builtin_amdgcn_s_setprio(0);
    }
  }
#undef STAGE

  // ---- epilogue: normalize, per-wave LDS transpose, coalesced store
  __syncthreads();   // all waves done with K-tile buffers
  const float invl = 1.f / lstate;
  char* wb = (char*)lds + wv * 4096;   // [q=32][d=64] bf16, XOR-swizzled rows
#pragma unroll
  for (int df = 0; df < 2; ++df)
#pragma unroll
    for (int t = 0; t < 4; ++t) {
      const f32x16& ov = df ? o1 : o0;
      bf16x4 pkt;
      pkt[0] = (bf16)(ov[4*t+0] * invl);
      pkt[1] = (bf16)(ov[4*t+1] * invl);
      pkt[2] = (bf16)(ov[4*t+2] * invl);
      pkt[3] = (bf16)(ov[4*t+3] * invl);
      const int byte = (l31 * 128 + df * 64 + t * 16 + h * 8) ^ ((l31 & 7) << 4);
      *(bf16x4*)(wb + byte) = pkt;
    }
  // same-wave read-back (no barrier needed), coalesced global store
#pragma unroll
  for (int ps = 0; ps < 4; ++ps) {
    const int qr = ps * 8 + (lane >> 3);
    const int byte = (qr * 128 + (lane & 7) * 16) ^ ((qr & 7) << 4);
    bf16x8 vv = *(const bf16x8*)(wb + byte);
    bf16* dst = ctx + (size_t)(b * SQ_ + q0 + qr) * DM_ + hd * 64 + (lane & 7) * 8;
    *(bf16x8*)dst = vv;
  }
}

// ------------------------------------------------- dual LayerNorm residual #1
__global__ __launch_bounds__(256) void dual_ln_kernel(const float* __restrict__ x,
                                                      const bf16* __restrict__ attn,
                                                      const float* __restrict__ g1,
                                                      const float* __restrict__ be1,
                                                      bf16* __restrict__ out) {
  const int row = blockIdx.x * 4 + (threadIdx.x >> 6);
  const int lane = threadIdx.x & 63;
  const float* xr = x + (size_t)row * DM_ + lane * 8;
  float xs[8], as_[8];
  float4 t0 = ((const float4*)xr)[0];
  float4 t1 = ((const float4*)xr)[1];
  xs[0] = t0.x; xs[1] = t0.y; xs[2] = t0.z; xs[3] = t0.w;
  xs[4] = t1.x; xs[5] = t1.y; xs[6] = t1.z; xs[7] = t1.w;
  bf16x8 av = *(const bf16x8*)(attn + (size_t)row * DM_ + lane * 8);
#pragma unroll
  for (int e = 0; e < 8; ++e) as_[e] = (float)av[e];
  float sx = 0, sx2 = 0, sa = 0, sa2 = 0;
#pragma unroll
  for (int e = 0; e < 8; ++e) {
    sx += xs[e]; sx2 += xs[e] * xs[e];
    sa += as_[e]; sa2 += as_[e] * as_[e];
  }
#pragma unroll
  for (int off = 1; off < 64; off <<= 1) {
    sx += __shfl_xor(sx, off);  sx2 += __shfl_xor(sx2, off);
    sa += __shfl_xor(sa, off);  sa2 += __shfl_xor(sa2, off);
  }
  const float inv = 1.f / (float)DM_;
  const float mux = sx * inv, mua = sa * inv;
  const float rx = rsqrtf(fmaxf(sx2 * inv - mux * mux, 0.f) + 1e-5f);
  const float ra = rsqrtf(fmaxf(sa2 * inv - mua * mua, 0.f) + 1e-5f);
  bf16x8 ov;
#pragma unroll
  for (int e = 0; e < 8; ++e) {
    const int c = lane * 8 + e;
    const float val = ((xs[e] - mux) * rx + (as_[e] - mua) * ra) * g1[c] + 2.f * be1[c];
    ov[e] = (bf16)val;
  }
  *(bf16x8*)(out + (size_t)row * DM_ + lane * 8) = ov;
}

// ------------------------------------------------------ final LN residual #2
__global__ __launch_bounds__(256) void final_ln_kernel(const bf16* __restrict__ x1,
                                                       const bf16* __restrict__ ffn,
                                                       const float* __restrict__ g2,
                                                       const float* __restrict__ be2,
                                                       float* __restrict__ out) {
  const int row = blockIdx.x * 4 + (threadIdx.x >> 6);
  const int lane = threadIdx.x & 63;
  bf16x8 xv = *(const bf16x8*)(x1 + (size_t)row * DM_ + lane * 8);
  bf16x8 fv = *(const bf16x8*)(ffn + (size_t)row * DM_ + lane * 8);
  float fs[8];
#pragma unroll
  for (int e = 0; e < 8; ++e) fs[e] = (float)fv[e];
  float sf = 0, sf2 = 0;
#pragma unroll
  for (int e = 0; e < 8; ++e) { sf += fs[e]; sf2 += fs[e] * fs[e]; }
#pragma unroll
  for (int off = 1; off < 64; off <<= 1) {
    sf += __shfl_xor(sf, off);  sf2 += __shfl_xor(sf2, off);
  }
  const float inv = 1.f / (float)DM_;
  const float mu = sf * inv;
  const float rs = rsqrtf(fmaxf(sf2 * inv - mu * mu, 0.f) + 1e-5f);
  float ov[8];
#pragma unroll
  for (int e = 0; e < 8; ++e) {
    const int c = lane * 8 + e;
    ov[e] = (float)xv[e] + (fs[e] - mu) * rs * g2[c] + be2[c];
  }
  float* orow = out + (size_t)row * DM_ + lane * 8;
  float4 o0 = {ov[0], ov[1], ov[2], ov[3]};
  float4 o1 = {ov[4], ov[5], ov[6], ov[7]};
  ((float4*)orow)[0] = o0;
  ((float4*)orow)[1] = o1;
}

// ---------------------------------------------------------------------------
extern "C" void kernel_launch(void* const* d_in, const int* in_sizes, int n_in,
                              void* d_out, int out_size, void* d_ws, size_t ws_size,
                              hipStream_t stream) {
  const float* x     = (const float*)d_in[0];
  const float* w_qkv = (const float*)d_in[1];
  const float* b_qkv = (const float*)d_in[2];
  const float* w_out = (const float*)d_in[3];
  const float* b_out = (const float*)d_in[4];
  const float* w1    = (const float*)d_in[5];
  const float* b1    = (const float*)d_in[6];
  const float* w2    = (const float*)d_in[7];
  const float* b2    = (const float*)d_in[8];
  const float* g1    = (const float*)d_in[9];
  const float* be1   = (const float*)d_in[10];
  const float* g2    = (const float*)d_in[11];
  const float* be2   = (const float*)d_in[12];
  float* out = (float*)d_out;

  char* ws = (char*)d_ws;
  const size_t o_wqkv = 0;
  const size_t o_wout = o_wqkv + (size_t)DM_ * DM_ * 2;
  const size_t o_w1   = o_wout + (size_t)DM_ * DM_ * 2;
  const size_t o_w2   = o_w1 + (size_t)DFF_ * DM_ * 2;
  const size_t o_A    = o_w2 + (size_t)DM_ * DFF_ * 2;     // x_bf -> ctx_bf
  const size_t o_B    = o_A + (size_t)ROWS_ * DM_ * 2;     // qkv_bf -> x1_bf
  const size_t o_C    = o_B + (size_t)ROWS_ * DM_ * 2;     // attn_bf -> ffn_bf
  const size_t o_D    = o_C + (size_t)ROWS_ * DM_ * 2;     // h1_bf [ROWS,DFF]
  const size_t need   = o_D + (size_t)ROWS_ * DFF_ * 2;
  if (ws_size < need) return;

  bf16* wqkv_bf = (bf16*)(ws + o_wqkv);
  bf16* wout_bf = (bf16*)(ws + o_wout);
  bf16* w1_bf   = (bf16*)(ws + o_w1);
  bf16* w2_bf   = (bf16*)(ws + o_w2);
  bf16* bufA    = (bf16*)(ws + o_A);
  bf16* bufB    = (bf16*)(ws + o_B);
  bf16* bufC    = (bf16*)(ws + o_C);
  bf16* bufD    = (bf16*)(ws + o_D);

  // 1. converts
  f2b_kernel<<<dim3((ROWS_ * DM_ / 8 + 255) / 256), dim3(256), 0, stream>>>(x, bufA, ROWS_ * DM_ / 8);
  f2b_kernel<<<dim3((DM_ * DM_ / 8 + 255) / 256), dim3(256), 0, stream>>>(w_qkv, wqkv_bf, DM_ * DM_ / 8);
  f2b_kernel<<<dim3((DM_ * DM_ / 8 + 255) / 256), dim3(256), 0, stream>>>(w_out, wout_bf, DM_ * DM_ / 8);
  f2b_kernel<<<dim3((DFF_ * DM_ / 8 + 255) / 256), dim3(256), 0, stream>>>(w1, w1_bf, DFF_ * DM_ / 8);
  f2b_kernel<<<dim3((DM_ * DFF_ / 8 + 255) / 256), dim3(256), 0, stream>>>(w2, w2_bf, DM_ * DFF_ / 8);

  // 2. qkv = x @ w_qkv.T + b_qkv       [16384,512]
  gemm_bt<0><<<dim3(DM_ / 128, ROWS_ / 128), dim3(256), 0, stream>>>(bufA, wqkv_bf, b_qkv, bufB, ROWS_, DM_, DM_);

  // 3. self-attention (Q=K=V=qkv) -> ctx
  attn_kernel<<<dim3(SQ_ / 128, NH_, BN_), dim3(256), 0, stream>>>(bufB, bufA);

  // 4. attn = ctx @ w_out.T + b_out
  gemm_bt<0><<<dim3(DM_ / 128, ROWS_ / 128), dim3(256), 0, stream>>>(bufA, wout_bf, b_out, bufC, ROWS_, DM_, DM_);

  // 5. x1 = LN(x) + LN(attn)
  dual_ln_kernel<<<dim3(ROWS_ / 4), dim3(256), 0, stream>>>(x, bufC, g1, be1, bufB);

  // 6. h1 = relu(x1 @ w1.T + b1)       [16384,2048]
  gemm_bt<1><<<dim3(DFF_ / 128, ROWS_ / 128), dim3(256), 0, stream>>>(bufB, w1_bf, b1, bufD, ROWS_, DFF_, DM_);

  // 7. ffn = h1 @ w2.T + b2            [16384,512]
  gemm_bt<0><<<dim3(DM_ / 128, ROWS_ / 128), dim3(256), 0, stream>>>(bufD, w2_bf, b2, bufC, ROWS_, DM_, DFF_);

  // 8. out = x1 + LN(ffn)
  final_ln_kernel<<<dim3(ROWS_ / 4), dim3(256), 0, stream>>>(bufB, bufC, g2, be2, out);
}

// Round 4
// 238.459 us; speedup vs baseline: 1.6261x; 1.0888x over previous
//
#include <hip/hip_runtime.h>
#include <hip/hip_bf16.h>
#include <stdint.h>

// ---------------------------------------------------------------------------
// EncoderLayer: x[16,1024,512] fp32; all matmuls in bf16 MFMA, fp32 accum.
// ---------------------------------------------------------------------------

using bf16 = __bf16;
typedef __attribute__((ext_vector_type(2))) __bf16 bf16x2;
typedef __attribute__((ext_vector_type(4))) __bf16 bf16x4;
typedef __attribute__((ext_vector_type(8))) __bf16 bf16x8;
typedef __attribute__((ext_vector_type(4))) float floatx4;
typedef __attribute__((ext_vector_type(16))) float f32x16;

#define AS1 __attribute__((address_space(1)))
#define AS3 __attribute__((address_space(3)))

#define L2E 1.44269504088896340736f

constexpr int BN_ = 16, SQ_ = 1024, DM_ = 512, DFF_ = 2048, NH_ = 8, DK_ = 64;
constexpr int ROWS_ = BN_ * SQ_;   // 16384

// ---------------------------------------------------------------- fp32->bf16
__global__ __launch_bounds__(256) void f2b_kernel(const float* __restrict__ in,
                                                  bf16* __restrict__ out, int n8) {
  int i = blockIdx.x * 256 + threadIdx.x;
  if (i >= n8) return;
  float4 a = ((const float4*)in)[2 * i];
  float4 b = ((const float4*)in)[2 * i + 1];
  bf16x8 o;
  o[0] = (bf16)a.x; o[1] = (bf16)a.y; o[2] = (bf16)a.z; o[3] = (bf16)a.w;
  o[4] = (bf16)b.x; o[5] = (bf16)b.y; o[6] = (bf16)b.z; o[7] = (bf16)b.w;
  ((bf16x8*)out)[i] = o;
}

// ------------------------------------------------------------------- GEMM
// C[M,N] = A[M,K] @ B[N,K]^T + bias, optional ReLU, bf16 out.
// 128x128 tile, BK=32, 4 waves each owning 64x64 (4x4 frags of 16x16x32).
// This round: double-buffered LDS (2x16KB) with counted vmcnt:
//   top of iter t: STAGE(t+1) into buf^1 (loads stay in flight a full iter),
//   vmcnt(4) -> my stage(t) loads landed; s_barrier -> everyone's landed;
//   compute buf[cur]; s_barrier -> safe to overwrite next iter.
// vmcnt never drained to 0 in the main loop (T4).
template <int RELU>
__global__ __launch_bounds__(256) void gemm_bt(const bf16* __restrict__ A,
                                               const bf16* __restrict__ B,
                                               const float* __restrict__ bias,
                                               bf16* __restrict__ C,
                                               int M, int N, int K) {
  __shared__ char glds[32768];   // [A dbuf 2x8KB][B dbuf 2x8KB]
  const int tid = threadIdx.x;
  const int lane = tid & 63;
  const int wv = tid >> 6;
  const int wr = wv >> 1, wc = wv & 1;
  const int r15 = lane & 15, g = lane >> 4;
  const int tileN = blockIdx.x * 128;
  const int tileM = blockIdx.y * 128;

  floatx4 acc[4][4] = {};

  // ---- staging precompute (proven swizzle: pslot ^ ((row>>1)&3))
  uint32_t dstoff[2];
  const bf16* srcA[2];
  const bf16* srcB[2];
#pragma unroll
  for (int is = 0; is < 2; ++is) {
    const int base = wv * 2048 + is * 1024;
    const int ob = base + lane * 16;
    const int row = ob >> 6;
    const int pslot = (ob >> 4) & 3;
    const int sslot = pslot ^ ((row >> 1) & 3);
    dstoff[is] = base;
    srcA[is] = A + (size_t)(tileM + row) * K + sslot * 8;
    srcB[is] = B + (size_t)(tileN + row) * K + sslot * 8;
  }

#define GSTAGE(buf, kt)                                                         \
  {                                                                             \
    _Pragma("unroll")                                                           \
    for (int is = 0; is < 2; ++is) {                                            \
      __builtin_amdgcn_global_load_lds(                                         \
          (AS1 uint32_t*)(srcA[is] + (kt) * 32),                                \
          (AS3 uint32_t*)((AS3 char*)glds + (buf) * 8192 + dstoff[is]), 16, 0, 0); \
      __builtin_amdgcn_global_load_lds(                                         \
          (AS1 uint32_t*)(srcB[is] + (kt) * 32),                                \
          (AS3 uint32_t*)((AS3 char*)glds + 16384 + (buf) * 8192 + dstoff[is]), \
          16, 0, 0);                                                            \
    }                                                                           \
  }

  // ---- fragment-read byte offsets (within one 8KB buffer), kt-invariant
  uint32_t aoff[4], boff[4];
#pragma unroll
  for (int m = 0; m < 4; ++m) {
    const int arow = wr * 64 + m * 16 + r15;
    aoff[m] = (uint32_t)((arow * 64 + g * 16) ^ (((arow >> 1) & 3) << 4));
  }
#pragma unroll
  for (int n = 0; n < 4; ++n) {
    const int brow = wc * 64 + n * 16 + r15;
    boff[n] = (uint32_t)((brow * 64 + g * 16) ^ (((brow >> 1) & 3) << 4));
  }

  const int nk = K >> 5;
  GSTAGE(0, 0);

  for (int kt = 0; kt < nk; ++kt) {
    const int cur = kt & 1;
    if (kt + 1 < nk) {
      GSTAGE(cur ^ 1, kt + 1);
      asm volatile("s_waitcnt vmcnt(4)" ::: "memory");   // tile kt's 4 loads done
    } else {
      asm volatile("s_waitcnt vmcnt(0)" ::: "memory");
    }
    __builtin_amdgcn_s_barrier();      // everyone's stage of buf[cur] visible
    __builtin_amdgcn_sched_barrier(0);

    const char* Ac = (const char*)glds + cur * 8192;
    const char* Bc = (const char*)glds + 16384 + cur * 8192;

    bf16x8 af[4], bfr[4];
#pragma unroll
    for (int m = 0; m < 4; ++m) af[m] = *(const bf16x8*)(Ac + aoff[m]);
#pragma unroll
    for (int n = 0; n < 4; ++n) bfr[n] = *(const bf16x8*)(Bc + boff[n]);
#pragma unroll
    for (int m = 0; m < 4; ++m)
#pragma unroll
      for (int n = 0; n < 4; ++n)
        acc[m][n] = __builtin_amdgcn_mfma_f32_16x16x32_bf16(af[m], bfr[n],
                                                            acc[m][n], 0, 0, 0);
    __builtin_amdgcn_s_barrier();      // reads of buf[cur] done -> re-stageable
  }
#undef GSTAGE

  // epilogue: D layout col = lane&15, row = (lane>>4)*4 + reg   [m89]
#pragma unroll
  for (int n = 0; n < 4; ++n) {
    const int col = tileN + wc * 64 + n * 16 + r15;
    const float bv = bias[col];
#pragma unroll
    for (int m = 0; m < 4; ++m) {
      const int row0 = tileM + wr * 64 + m * 16 + g * 4;
#pragma unroll
      for (int j = 0; j < 4; ++j) {
        float v = acc[m][n][j] + bv;
        if (RELU) v = fmaxf(v, 0.f);
        C[(size_t)(row0 + j) * N + col] = (bf16)v;
      }
    }
  }
}

// ----------------------------------------------------------- flash attention
// Q = K = V = qkv[b,:,h*64:(h+1)*64].  One block = 128 q-rows of one (b,h).
// 4 waves x 32 q-rows, KVBLK=64, 32x32x16 MFMA, swapped operands.
// log2-domain softmax, permlane32_swap P-pack, defer-max, double-buffered
// K tile with counted vmcnt + raw s_barrier. (unchanged this round)
__global__ __launch_bounds__(256) void attn_kernel(const bf16* __restrict__ qkv,
                                                   bf16* __restrict__ ctx) {
  __shared__ char lds[16384];   // 2 x 8KB K-tile double buffer; epilogue reuses

  const int tid = threadIdx.x;
  const int lane = tid & 63;
  const int wv = tid >> 6;
  const int l31 = lane & 31;
  const int h = lane >> 5;                 // k-half for 32x32x16 operands
  const int b = blockIdx.z, hd = blockIdx.y, qt = blockIdx.x;
  const size_t headoff = (size_t)b * SQ_ * DM_ + hd * DK_;
  const int q0 = qt * 128 + wv * 32;

  // ---- Q fragments (B operand): Q[q=l31][d=16*kd+8*h+e] * (0.125 * log2 e)
  const float QS = 0.125f * L2E;
  bf16x8 aq[4];
#pragma unroll
  for (int kd = 0; kd < 4; ++kd) {
    const bf16* gq = qkv + headoff + (size_t)(q0 + l31) * DM_ + kd * 16 + h * 8;
    bf16x8 v = *(const bf16x8*)gq;
#pragma unroll
    for (int e = 0; e < 8; ++e) v[e] = (bf16)((float)v[e] * QS);
    aq[kd] = v;
  }

  f32x16 o0 = {}, o1 = {};                 // Ot[d,q]: df=0,1 (d-halves)
  float mstate = -1e30f, lstate = 0.f;

  const uint32_t ldsb = (uint32_t)(uintptr_t)(AS3 char*)lds;

  // ---- staging address precompute (tile-relative; subtiled layout)
  uint32_t dstoff[2];
  const bf16* srcb[2];
#pragma unroll
  for (int is = 0; is < 2; ++is) {
    const int ob = is * 4096 + wv * 1024 + lane * 16;
    const int e0 = ob >> 1;
    const int srow = ((e0 >> 8) << 2) + ((e0 >> 4) & 3);
    const int dcol = ((e0 >> 6) & 3) * 16 + ((e0 >> 3) & 1) * 8;
    dstoff[is] = is * 4096 + wv * 1024;    // wave-uniform LDS base
    srcb[is] = qkv + headoff + (size_t)srow * DM_ + dcol;
  }

#define STAGE(buf, t)                                                          \
  {                                                                            \
    _Pragma("unroll")                                                          \
    for (int is = 0; is < 2; ++is) {                                           \
      __builtin_amdgcn_global_load_lds(                                        \
          (AS1 uint32_t*)(srcb[is] + (size_t)(t) * 64 * DM_),                  \
          (AS3 uint32_t*)((AS3 char*)lds + (buf) * 8192 + dstoff[is]), 16, 0, 0); \
    }                                                                          \
  }

  constexpr int NT = SQ_ / 64;   // 16
  STAGE(0, 0);

  for (int t = 0; t < NT; ++t) {
    const int cur = t & 1;
    // barrier #1: all waves done reading buf[cur^1] (iter t-1) -> safe to overwrite
    __builtin_amdgcn_s_barrier();
    if (t + 1 < NT) {
      STAGE(cur ^ 1, t + 1);
      asm volatile("s_waitcnt vmcnt(2)" ::: "memory");   // tile t's 2 loads done
    } else {
      asm volatile("s_waitcnt vmcnt(0)" ::: "memory");
    }
    // barrier #2: all waves' stage of buf[cur] visible
    __builtin_amdgcn_s_barrier();
    __builtin_amdgcn_sched_barrier(0);

    const char* tile = (const char*)lds + cur * 8192;

    // ---- S^T = K · Q^T (log2 domain): A = K rows (subtiled), B = aq
    f32x16 s0v = {}, s1v = {};
    const char* pabase = tile + (l31 >> 2) * 512 + (l31 & 3) * 32 + h * 16;
    __builtin_amdgcn_s_setprio(1);
#pragma unroll
    for (int kd = 0; kd < 4; ++kd) {
      bf16x8 a0 = *(const bf16x8*)(pabase + kd * 128);
      bf16x8 a1 = *(const bf16x8*)(pabase + kd * 128 + 4096);
      s0v = __builtin_amdgcn_mfma_f32_32x32x16_bf16(a0, aq[kd], s0v, 0, 0, 0);
      s1v = __builtin_amdgcn_mfma_f32_32x32x16_bf16(a1, aq[kd], s1v, 0, 0, 0);
    }
    __builtin_amdgcn_s_setprio(0);

    // ---- online softmax, log2 domain; lane owns q = l31
    float mx = s0v[0];
#pragma unroll
    for (int r = 1; r < 16; ++r) mx = fmaxf(mx, s0v[r]);
#pragma unroll
    for (int r = 0; r < 16; ++r) mx = fmaxf(mx, s1v[r]);
    mx = fmaxf(mx, __shfl_xor(mx, 32));
    // defer-max (T13): only rescale when max grew by > 8 (log2 units)
    if (!__all(mx - mstate <= 8.f)) {
      const float nm = fmaxf(mstate, mx);
      const float al = exp2f(mstate - nm);
      mstate = nm;
      lstate *= al;
#pragma unroll
      for (int r = 0; r < 16; ++r) { o0[r] *= al; o1[r] *= al; }
    }
    float rs = 0.f;
#pragma unroll
    for (int r = 0; r < 16; ++r) {
      float p = exp2f(s0v[r] - mstate);
      s0v[r] = p; rs += p;
    }
#pragma unroll
    for (int r = 0; r < 16; ++r) {
      float p = exp2f(s1v[r] - mstate);
      s1v[r] = p; rs += p;
    }
    rs += __shfl_xor(rs, 32);
    lstate += rs;

    // ---- build PV B-fragments in registers: bf16 pairs + permlane32_swap
    uint32_t pf[4][4];
#pragma unroll
    for (int ks = 0; ks < 4; ++ks) {
      const int kb = (ks & 1) * 8;
      float v0, v1, v2, v3, v4, v5, v6, v7;
      if (ks < 2) {
        v0 = s0v[kb+0]; v1 = s0v[kb+1]; v2 = s0v[kb+2]; v3 = s0v[kb+3];
        v4 = s0v[kb+4]; v5 = s0v[kb+5]; v6 = s0v[kb+6]; v7 = s0v[kb+7];
      } else {
        v0 = s1v[kb+0]; v1 = s1v[kb+1]; v2 = s1v[kb+2]; v3 = s1v[kb+3];
        v4 = s1v[kb+4]; v5 = s1v[kb+5]; v6 = s1v[kb+6]; v7 = s1v[kb+7];
      }
      union { bf16x2 v; uint32_t u; } P0, P1, P2, P3;
      P0.v = bf16x2{(bf16)v0, (bf16)v1};
      P1.v = bf16x2{(bf16)v2, (bf16)v3};
      P2.v = bf16x2{(bf16)v4, (bf16)v5};
      P3.v = bf16x2{(bf16)v6, (bf16)v7};
      asm volatile("v_permlane32_swap_b32 %0, %1" : "+v"(P0.u), "+v"(P2.u));
      asm volatile("v_permlane32_swap_b32 %0, %1" : "+v"(P1.u), "+v"(P3.u));
      pf[ks][0] = P0.u;
      pf[ks][1] = P1.u;
      pf[ks][2] = P2.u;
      pf[ks][3] = P3.u;
    }

    // ---- PV: Ot[d,q] += V^T-rows (tr-read) x P^T
#pragma unroll
    for (int df = 0; df < 2; ++df) {
      const uint32_t vb = ldsb + cur * 8192 + df * 256 + (lane & 15) * 8 +
                          ((lane >> 4) & 1) * 128 + (lane >> 5) * 1024;
      bf16x4 lo[4], hi[4];
#pragma unroll
      for (int ks = 0; ks < 4; ++ks) {
        asm volatile("ds_read_b64_tr_b16 %0, %2\n\t"
                     "ds_read_b64_tr_b16 %1, %2 offset:512"
                     : "=&v"(lo[ks]), "=&v"(hi[ks])
                     : "v"(vb + ks * 2048));
      }
      asm volatile("s_waitcnt lgkmcnt(0)" ::: "memory");
      __builtin_amdgcn_sched_barrier(0);
      __builtin_amdgcn_s_setprio(1);
#pragma unroll
      for (int ks = 0; ks < 4; ++ks) {
        union { struct { bf16x4 l, h; } p; bf16x8 v; } av;
        av.p.l = lo[ks]; av.p.h = hi[ks];
        union { uint32_t u[4]; bf16x8 v; } bv;
        bv.u[0] = pf[ks][0]; bv.u[1] = pf[ks][1];
        bv.u[2] = pf[ks][2]; bv.u[3] = pf[ks][3];
        if (df == 0)
          o0 = __builtin_amdgcn_mfma_f32_32x32x16_bf16(av.v, bv.v, o0, 0, 0, 0);
        else
          o1 = __builtin_amdgcn_mfma_f32_32x32x16_bf16(av.v, bv.v, o1, 0, 0, 0);
      }
      __builtin_amdgcn_s_setprio(0);
    }
  }
#undef STAGE

  // ---- epilogue: normalize, per-wave LDS transpose, coalesced store
  __syncthreads();   // all waves done with K-tile buffers
  const float invl = 1.f / lstate;
  char* wb = (char*)lds + wv * 4096;   // [q=32][d=64] bf16, XOR-swizzled rows
#pragma unroll
  for (int df = 0; df < 2; ++df)
#pragma unroll
    for (int t = 0; t < 4; ++t) {
      const f32x16& ov = df ? o1 : o0;
      bf16x4 pkt;
      pkt[0] = (bf16)(ov[4*t+0] * invl);
      pkt[1] = (bf16)(ov[4*t+1] * invl);
      pkt[2] = (bf16)(ov[4*t+2] * invl);
      pkt[3] = (bf16)(ov[4*t+3] * invl);
      const int byte = (l31 * 128 + df * 64 + t * 16 + h * 8) ^ ((l31 & 7) << 4);
      *(bf16x4*)(wb + byte) = pkt;
    }
  // same-wave read-back (no barrier needed), coalesced global store
#pragma unroll
  for (int ps = 0; ps < 4; ++ps) {
    const int qr = ps * 8 + (lane >> 3);
    const int byte = (qr * 128 + (lane & 7) * 16) ^ ((qr & 7) << 4);
    bf16x8 vv = *(const bf16x8*)(wb + byte);
    bf16* dst = ctx + (size_t)(b * SQ_ + q0 + qr) * DM_ + hd * 64 + (lane & 7) * 8;
    *(bf16x8*)dst = vv;
  }
}

// ------------------------------------------------- dual LayerNorm residual #1
__global__ __launch_bounds__(256) void dual_ln_kernel(const float* __restrict__ x,
                                                      const bf16* __restrict__ attn,
                                                      const float* __restrict__ g1,
                                                      const float* __restrict__ be1,
                                                      bf16* __restrict__ out) {
  const int row = blockIdx.x * 4 + (threadIdx.x >> 6);
  const int lane = threadIdx.x & 63;
  const float* xr = x + (size_t)row * DM_ + lane * 8;
  float xs[8], as_[8];
  float4 t0 = ((const float4*)xr)[0];
  float4 t1 = ((const float4*)xr)[1];
  xs[0] = t0.x; xs[1] = t0.y; xs[2] = t0.z; xs[3] = t0.w;
  xs[4] = t1.x; xs[5] = t1.y; xs[6] = t1.z; xs[7] = t1.w;
  bf16x8 av = *(const bf16x8*)(attn + (size_t)row * DM_ + lane * 8);
#pragma unroll
  for (int e = 0; e < 8; ++e) as_[e] = (float)av[e];
  float sx = 0, sx2 = 0, sa = 0, sa2 = 0;
#pragma unroll
  for (int e = 0; e < 8; ++e) {
    sx += xs[e]; sx2 += xs[e] * xs[e];
    sa += as_[e]; sa2 += as_[e] * as_[e];
  }
#pragma unroll
  for (int off = 1; off < 64; off <<= 1) {
    sx += __shfl_xor(sx, off);  sx2 += __shfl_xor(sx2, off);
    sa += __shfl_xor(sa, off);  sa2 += __shfl_xor(sa2, off);
  }
  const float inv = 1.f / (float)DM_;
  const float mux = sx * inv, mua = sa * inv;
  const float rx = rsqrtf(fmaxf(sx2 * inv - mux * mux, 0.f) + 1e-5f);
  const float ra = rsqrtf(fmaxf(sa2 * inv - mua * mua, 0.f) + 1e-5f);
  bf16x8 ov;
#pragma unroll
  for (int e = 0; e < 8; ++e) {
    const int c = lane * 8 + e;
    const float val = ((xs[e] - mux) * rx + (as_[e] - mua) * ra) * g1[c] + 2.f * be1[c];
    ov[e] = (bf16)val;
  }
  *(bf16x8*)(out + (size_t)row * DM_ + lane * 8) = ov;
}

// ------------------------------------------------------ final LN residual #2
__global__ __launch_bounds__(256) void final_ln_kernel(const bf16* __restrict__ x1,
                                                       const bf16* __restrict__ ffn,
                                                       const float* __restrict__ g2,
                                                       const float* __restrict__ be2,
                                                       float* __restrict__ out) {
  const int row = blockIdx.x * 4 + (threadIdx.x >> 6);
  const int lane = threadIdx.x & 63;
  bf16x8 xv = *(const bf16x8*)(x1 + (size_t)row * DM_ + lane * 8);
  bf16x8 fv = *(const bf16x8*)(ffn + (size_t)row * DM_ + lane * 8);
  float fs[8];
#pragma unroll
  for (int e = 0; e < 8; ++e) fs[e] = (float)fv[e];
  float sf = 0, sf2 = 0;
#pragma unroll
  for (int e = 0; e < 8; ++e) { sf += fs[e]; sf2 += fs[e] * fs[e]; }
#pragma unroll
  for (int off = 1; off < 64; off <<= 1) {
    sf += __shfl_xor(sf, off);  sf2 += __shfl_xor(sf2, off);
  }
  const float inv = 1.f / (float)DM_;
  const float mu = sf * inv;
  const float rs = rsqrtf(fmaxf(sf2 * inv - mu * mu, 0.f) + 1e-5f);
  float ov[8];
#pragma unroll
  for (int e = 0; e < 8; ++e) {
    const int c = lane * 8 + e;
    ov[e] = (float)xv[e] + (fs[e] - mu) * rs * g2[c] + be2[c];
  }
  float* orow = out + (size_t)row * DM_ + lane * 8;
  float4 o0 = {ov[0], ov[1], ov[2], ov[3]};
  float4 o1 = {ov[4], ov[5], ov[6], ov[7]};
  ((float4*)orow)[0] = o0;
  ((float4*)orow)[1] = o1;
}

// ---------------------------------------------------------------------------
extern "C" void kernel_launch(void* const* d_in, const int* in_sizes, int n_in,
                              void* d_out, int out_size, void* d_ws, size_t ws_size,
                              hipStream_t stream) {
  const float* x     = (const float*)d_in[0];
  const float* w_qkv = (const float*)d_in[1];
  const float* b_qkv = (const float*)d_in[2];
  const float* w_out = (const float*)d_in[3];
  const float* b_out = (const float*)d_in[4];
  const float* w1    = (const float*)d_in[5];
  const float* b1    = (const float*)d_in[6];
  const float* w2    = (const float*)d_in[7];
  const float* b2    = (const float*)d_in[8];
  const float* g1    = (const float*)d_in[9];
  const float* be1   = (const float*)d_in[10];
  const float* g2    = (const float*)d_in[11];
  const float* be2   = (const float*)d_in[12];
  float* out = (float*)d_out;

  char* ws = (char*)d_ws;
  const size_t o_wqkv = 0;
  const size_t o_wout = o_wqkv + (size_t)DM_ * DM_ * 2;
  const size_t o_w1   = o_wout + (size_t)DM_ * DM_ * 2;
  const size_t o_w2   = o_w1 + (size_t)DFF_ * DM_ * 2;
  const size_t o_A    = o_w2 + (size_t)DM_ * DFF_ * 2;     // x_bf -> ctx_bf
  const size_t o_B    = o_A + (size_t)ROWS_ * DM_ * 2;     // qkv_bf -> x1_bf
  const size_t o_C    = o_B + (size_t)ROWS_ * DM_ * 2;     // attn_bf -> ffn_bf
  const size_t o_D    = o_C + (size_t)ROWS_ * DM_ * 2;     // h1_bf [ROWS,DFF]
  const size_t need   = o_D + (size_t)ROWS_ * DFF_ * 2;
  if (ws_size < need) return;

  bf16* wqkv_bf = (bf16*)(ws + o_wqkv);
  bf16* wout_bf = (bf16*)(ws + o_wout);
  bf16* w1_bf   = (bf16*)(ws + o_w1);
  bf16* w2_bf   = (bf16*)(ws + o_w2);
  bf16* bufA    = (bf16*)(ws + o_A);
  bf16* bufB    = (bf16*)(ws + o_B);
  bf16* bufC    = (bf16*)(ws + o_C);
  bf16* bufD    = (bf16*)(ws + o_D);

  // 1. converts
  f2b_kernel<<<dim3((ROWS_ * DM_ / 8 + 255) / 256), dim3(256), 0, stream>>>(x, bufA, ROWS_ * DM_ / 8);
  f2b_kernel<<<dim3((DM_ * DM_ / 8 + 255) / 256), dim3(256), 0, stream>>>(w_qkv, wqkv_bf, DM_ * DM_ / 8);
  f2b_kernel<<<dim3((DM_ * DM_ / 8 + 255) / 256), dim3(256), 0, stream>>>(w_out, wout_bf, DM_ * DM_ / 8);
  f2b_kernel<<<dim3((DFF_ * DM_ / 8 + 255) / 256), dim3(256), 0, stream>>>(w1, w1_bf, DFF_ * DM_ / 8);
  f2b_kernel<<<dim3((DM_ * DFF_ / 8 + 255) / 256), dim3(256), 0, stream>>>(w2, w2_bf, DM_ * DFF_ / 8);

  // 2. qkv = x @ w_qkv.T + b_qkv       [16384,512]
  gemm_bt<0><<<dim3(DM_ / 128, ROWS_ / 128), dim3(256), 0, stream>>>(bufA, wqkv_bf, b_qkv, bufB, ROWS_, DM_, DM_);

  // 3. self-attention (Q=K=V=qkv) -> ctx
  attn_kernel<<<dim3(SQ_ / 128, NH_, BN_), dim3(256), 0, stream>>>(bufB, bufA);

  // 4. attn = ctx @ w_out.T + b_out
  gemm_bt<0><<<dim3(DM_ / 128, ROWS_ / 128), dim3(256), 0, stream>>>(bufA, wout_bf, b_out, bufC, ROWS_, DM_, DM_);

  // 5. x1 = LN(x) + LN(attn)
  dual_ln_kernel<<<dim3(ROWS_ / 4), dim3(256), 0, stream>>>(x, bufC, g1, be1, bufB);

  // 6. h1 = relu(x1 @ w1.T + b1)       [16384,2048]
  gemm_bt<1><<<dim3(DFF_ / 128, ROWS_ / 128), dim3(256), 0, stream>>>(bufB, w1_bf, b1, bufD, ROWS_, DFF_, DM_);

  // 7. ffn = h1 @ w2.T + b2            [16384,512]
  gemm_bt<0><<<dim3(DM_ / 128, ROWS_ / 128), dim3(256), 0, stream>>>(bufD, w2_bf, b2, bufC, ROWS_, DM_, DFF_);

  // 8. out = x1 + LN(ffn)
  final_ln_kernel<<<dim3(ROWS_ / 4), dim3(256), 0, stream>>>(bufB, bufC, g2, be2, out);
}